// Round 1
// baseline (536.957 us; speedup 1.0000x reference)
//
#include <hip/hip_runtime.h>

// Qwen3 MoE experts: per-expert SwiGLU MLP.
//   gate = rin @ gate_proj^T ; up = rin @ up_proj^T
//   hidden = silu(gate) * up ; out = hidden @ down_proj^T
// E=32, T=512, H=2048, I=768. Inputs f32; compute in bf16 MFMA (f32 accum).
// ws usage: hidden [E][T][I] bf16 = 24 MB.

#define NE 32
#define NT 512
#define NH 2048
#define NI 768

typedef short  short8  __attribute__((ext_vector_type(8)));
typedef float  floatx4 __attribute__((ext_vector_type(4)));
typedef ushort ushortx4 __attribute__((ext_vector_type(4)));

// f32 -> bf16 (round-to-nearest-even), bit pattern as ushort.
__device__ __forceinline__ ushort f2bf(float f) {
    union { float f; unsigned int u; } v; v.f = f;
    unsigned int r = v.u + 0x7fffu + ((v.u >> 16) & 1u);
    return (ushort)(r >> 16);
}

// ---------------------------------------------------------------------------
// Kernel 1: fused gate+up GEMMs + SwiGLU -> hidden (bf16).
// Tile: BM=128 (T) x BN=128 (I), BK=32 over H. 256 threads = 4 waves (2x2),
// each wave owns a 64x64 sub-tile = 4x4 fragments of 16x16.
// Both operands are row-major with K contiguous (NT GEMM).
// ---------------------------------------------------------------------------
__global__ __launch_bounds__(256) void moe_gateup(
    const float* __restrict__ rin, const float* __restrict__ gate,
    const float* __restrict__ up, ushort* __restrict__ hidden)
{
    // +8 ushort pad per row: stride 80 B = 20 banks -> only 2-way conflicts.
    __shared__ ushort As[128][40];
    __shared__ ushort Bgs[128][40];
    __shared__ ushort Bus[128][40];

    const int ti = blockIdx.x;   // I tile: 0..5
    const int tm = blockIdx.y;   // T tile: 0..3
    const int e  = blockIdx.z;   // expert

    const int tid  = threadIdx.x;
    const int lane = tid & 63;
    const int wave = tid >> 6;
    const int wr = wave >> 1, wc = wave & 1;

    const float* Ab = rin  + (size_t)e * NT * NH + (size_t)(tm * 128) * NH;
    const float* Gb = gate + (size_t)e * NI * NH + (size_t)(ti * 128) * NH;
    const float* Ub = up   + (size_t)e * NI * NH + (size_t)(ti * 128) * NH;

    // staging map: 128 rows x 32 cols f32; thread -> 4 rows of float4
    const int srow = tid >> 3;        // 0..31
    const int scol = (tid & 7) * 4;   // 0..28

    floatx4 accg[4][4], accu[4][4];
    #pragma unroll
    for (int m = 0; m < 4; ++m)
        #pragma unroll
        for (int n = 0; n < 4; ++n) {
            accg[m][n] = (floatx4)0.f;
            accu[m][n] = (floatx4)0.f;
        }

    const int frow = lane & 15;          // fragment row/col within 16
    const int kofs = (lane >> 4) * 8;    // k offset: 8 contiguous bf16 per lane

    for (int kt = 0; kt < NH / 32; ++kt) {
        const int k0 = kt * 32;
        floatx4 va[4], vg[4], vu[4];
        #pragma unroll
        for (int r = 0; r < 4; ++r) {
            const int row = srow + r * 32;
            va[r] = *(const floatx4*)(Ab + (size_t)row * NH + k0 + scol);
            vg[r] = *(const floatx4*)(Gb + (size_t)row * NH + k0 + scol);
            vu[r] = *(const floatx4*)(Ub + (size_t)row * NH + k0 + scol);
        }
        __syncthreads();   // previous iteration's LDS reads complete
        #pragma unroll
        for (int r = 0; r < 4; ++r) {
            const int row = srow + r * 32;
            ushortx4 a4, g4, u4;
            #pragma unroll
            for (int j = 0; j < 4; ++j) {
                a4[j] = f2bf(va[r][j]);
                g4[j] = f2bf(vg[r][j]);
                u4[j] = f2bf(vu[r][j]);
            }
            *(ushortx4*)&As [row][scol] = a4;
            *(ushortx4*)&Bgs[row][scol] = g4;
            *(ushortx4*)&Bus[row][scol] = u4;
        }
        __syncthreads();   // tile staged

        short8 af[4], gf[4], uf[4];
        #pragma unroll
        for (int m = 0; m < 4; ++m)
            af[m] = *(const short8*)&As[wr * 64 + m * 16 + frow][kofs];
        #pragma unroll
        for (int n = 0; n < 4; ++n) {
            gf[n] = *(const short8*)&Bgs[wc * 64 + n * 16 + frow][kofs];
            uf[n] = *(const short8*)&Bus[wc * 64 + n * 16 + frow][kofs];
        }
        #pragma unroll
        for (int m = 0; m < 4; ++m)
            #pragma unroll
            for (int n = 0; n < 4; ++n) {
                accg[m][n] = __builtin_amdgcn_mfma_f32_16x16x32_bf16(
                    af[m], gf[n], accg[m][n], 0, 0, 0);
                accu[m][n] = __builtin_amdgcn_mfma_f32_16x16x32_bf16(
                    af[m], uf[n], accu[m][n], 0, 0, 0);
            }
    }

    // Epilogue: silu(gate)*up -> bf16 hidden. C/D layout (m89):
    // col = lane&15, row = (lane>>4)*4 + reg.
    const int ccol  = lane & 15;
    const int crow0 = (lane >> 4) * 4;
    const size_t hbase = ((size_t)e * NT + (size_t)tm * 128) * NI + ti * 128;
    #pragma unroll
    for (int m = 0; m < 4; ++m)
        #pragma unroll
        for (int n = 0; n < 4; ++n)
            #pragma unroll
            for (int j = 0; j < 4; ++j) {
                const float g = accg[m][n][j];
                const float u = accu[m][n][j];
                const float h = (g / (1.f + __expf(-g))) * u;
                const int row = wr * 64 + m * 16 + crow0 + j;
                const int col = wc * 64 + n * 16 + ccol;
                hidden[hbase + (size_t)row * NI + col] = f2bf(h);
            }
}

// ---------------------------------------------------------------------------
// Kernel 2: down projection. A = hidden [T,I] bf16, B = down [H,I] f32.
// Same tile structure; BK=32 over I.
// ---------------------------------------------------------------------------
__global__ __launch_bounds__(256) void moe_down(
    const ushort* __restrict__ hidden, const float* __restrict__ down,
    float* __restrict__ out)
{
    __shared__ ushort As[128][40];
    __shared__ ushort Bs[128][40];

    const int tn = blockIdx.x;   // H tile: 0..15
    const int tm = blockIdx.y;   // T tile: 0..3
    const int e  = blockIdx.z;

    const int tid  = threadIdx.x;
    const int lane = tid & 63;
    const int wave = tid >> 6;
    const int wr = wave >> 1, wc = wave & 1;

    const ushort* Ab = hidden + ((size_t)e * NT + (size_t)tm * 128) * NI;
    const float*  Bb = down + (size_t)e * NH * NI + (size_t)(tn * 128) * NI;

    // A staging: bf16 source, 128x32; thread -> 2 chunks of 8 bf16 (16 B)
    const int a_row = tid >> 2;        // 0..63
    const int a_col = (tid & 3) * 8;   // 0,8,16,24
    // B staging: f32 source, like kernel 1
    const int srow = tid >> 3;
    const int scol = (tid & 7) * 4;

    floatx4 acc[4][4];
    #pragma unroll
    for (int m = 0; m < 4; ++m)
        #pragma unroll
        for (int n = 0; n < 4; ++n) acc[m][n] = (floatx4)0.f;

    const int frow = lane & 15;
    const int kofs = (lane >> 4) * 8;

    for (int kt = 0; kt < NI / 32; ++kt) {
        const int k0 = kt * 32;
        floatx4 ha0, ha1, vb[4];
        ha0 = *(const floatx4*)(Ab + (size_t)a_row * NI + k0 + a_col);
        ha1 = *(const floatx4*)(Ab + (size_t)(a_row + 64) * NI + k0 + a_col);
        #pragma unroll
        for (int r = 0; r < 4; ++r)
            vb[r] = *(const floatx4*)(Bb + (size_t)(srow + r * 32) * NI + k0 + scol);
        __syncthreads();
        *(floatx4*)&As[a_row][a_col]      = ha0;
        *(floatx4*)&As[a_row + 64][a_col] = ha1;
        #pragma unroll
        for (int r = 0; r < 4; ++r) {
            ushortx4 b4;
            #pragma unroll
            for (int j = 0; j < 4; ++j) b4[j] = f2bf(vb[r][j]);
            *(ushortx4*)&Bs[srow + r * 32][scol] = b4;
        }
        __syncthreads();

        short8 af[4], bf[4];
        #pragma unroll
        for (int m = 0; m < 4; ++m)
            af[m] = *(const short8*)&As[wr * 64 + m * 16 + frow][kofs];
        #pragma unroll
        for (int n = 0; n < 4; ++n)
            bf[n] = *(const short8*)&Bs[wc * 64 + n * 16 + frow][kofs];
        #pragma unroll
        for (int m = 0; m < 4; ++m)
            #pragma unroll
            for (int n = 0; n < 4; ++n)
                acc[m][n] = __builtin_amdgcn_mfma_f32_16x16x32_bf16(
                    af[m], bf[n], acc[m][n], 0, 0, 0);
    }

    const int ccol  = lane & 15;
    const int crow0 = (lane >> 4) * 4;
    float* Ob = out + ((size_t)e * NT + (size_t)tm * 128) * NH + tn * 128;
    #pragma unroll
    for (int m = 0; m < 4; ++m)
        #pragma unroll
        for (int n = 0; n < 4; ++n)
            #pragma unroll
            for (int j = 0; j < 4; ++j) {
                const int row = wr * 64 + m * 16 + crow0 + j;
                const int col = wc * 64 + n * 16 + ccol;
                Ob[(size_t)row * NH + col] = acc[m][n][j];
            }
}

extern "C" void kernel_launch(void* const* d_in, const int* in_sizes, int n_in,
                              void* d_out, int out_size, void* d_ws, size_t ws_size,
                              hipStream_t stream) {
    const float* rin  = (const float*)d_in[0];   // [E,T,H]
    const float* gate = (const float*)d_in[1];   // [E,I,H]
    const float* up   = (const float*)d_in[2];   // [E,I,H]
    const float* down = (const float*)d_in[3];   // [E,H,I]
    float* out = (float*)d_out;                  // [E*T, H]
    ushort* hidden = (ushort*)d_ws;              // [E,T,I] bf16, 24 MB

    dim3 blk(256);
    moe_gateup<<<dim3(NI / 128, NT / 128, NE), blk, 0, stream>>>(rin, gate, up, hidden);
    moe_down<<<dim3(NH / 128, NT / 128, NE), blk, 0, stream>>>(hidden, down, out);
}

// Round 2
// 402.625 us; speedup vs baseline: 1.3336x; 1.3336x over previous
//
#include <hip/hip_runtime.h>

// Qwen3 MoE experts: per-expert SwiGLU MLP.
//   gate = rin @ gate_proj^T ; up = rin @ up_proj^T
//   hidden = silu(gate) * up ; out = hidden @ down_proj^T
// E=32, T=512, H=2048, I=768. Inputs f32; compute in bf16 MFMA (f32 accum).
// ws: hidden [E][T][I] bf16 = 24 MB.
//
// R1: register-prefetch pipeline (global->VGPR issued before compute phase),
//     raw s_barrier + explicit lgkmcnt (avoid vmcnt(0) drain of prefetch),
//     v_cvt_pk_bf16_f32 for f32->bf16 staging, XCD-bijective block swizzle.

#define NE 32
#define NT 512
#define NH 2048
#define NI 768

typedef short        short8  __attribute__((ext_vector_type(8)));
typedef float        floatx4 __attribute__((ext_vector_type(4)));
typedef unsigned int uintx2  __attribute__((ext_vector_type(2)));

__device__ __forceinline__ unsigned int cvt_pk_bf16(float lo, float hi) {
    unsigned int r;
    asm("v_cvt_pk_bf16_f32 %0, %1, %2" : "=v"(r) : "v"(lo), "v"(hi));
    return r;   // low 16 = bf16(lo), high 16 = bf16(hi)
}

__device__ __forceinline__ uintx2 pack4(floatx4 v) {
    uintx2 r;
    r[0] = cvt_pk_bf16(v[0], v[1]);
    r[1] = cvt_pk_bf16(v[2], v[3]);
    return r;
}

// scalar f32->bf16 RNE for the epilogue (non-contiguous elements)
__device__ __forceinline__ ushort f2bf(float f) {
    union { float f; unsigned int u; } v; v.f = f;
    unsigned int r = v.u + 0x7fffu + ((v.u >> 16) & 1u);
    return (ushort)(r >> 16);
}

// ---------------------------------------------------------------------------
// Kernel 1: fused gate+up GEMMs + SwiGLU -> hidden (bf16).
// BM=128 (T) x BN=128 (I), BK=32 over H. 256 thr = 4 waves (2x2), each wave
// 64x64 = 4x4 frags of mfma_f32_16x16x32_bf16. NT layout (K contiguous).
// ---------------------------------------------------------------------------
__global__ __launch_bounds__(256) void moe_gateup(
    const float* __restrict__ rin, const float* __restrict__ gate,
    const float* __restrict__ up, ushort* __restrict__ hidden)
{
    __shared__ ushort As[128][40];   // +8 pad: stride 80B -> <=2-way conflicts
    __shared__ ushort Bgs[128][40];
    __shared__ ushort Bus[128][40];

    // XCD-bijective swizzle of flattened grid (768 blocks, 768%8==0, chunk 96)
    const int bid = blockIdx.x;
    const int wg  = (bid & 7) * (768 / 8) + (bid >> 3);
    const int e   = wg / 24;
    const int rem = wg % 24;
    const int ti  = rem % 6;    // I tile
    const int tm  = rem / 6;    // T tile

    const int tid  = threadIdx.x;
    const int lane = tid & 63;
    const int wave = tid >> 6;
    const int wr = wave >> 1, wc = wave & 1;

    const float* Ab = rin  + (size_t)e * NT * NH + (size_t)(tm * 128) * NH;
    const float* Gb = gate + (size_t)e * NI * NH + (size_t)(ti * 128) * NH;
    const float* Ub = up   + (size_t)e * NI * NH + (size_t)(ti * 128) * NH;

    const int srow = tid >> 3;        // 0..31
    const int scol = (tid & 7) * 4;   // 0..28

    floatx4 accg[4][4], accu[4][4];
    #pragma unroll
    for (int m = 0; m < 4; ++m)
        #pragma unroll
        for (int n = 0; n < 4; ++n) {
            accg[m][n] = (floatx4)0.f;
            accu[m][n] = (floatx4)0.f;
        }

    const int frow = lane & 15;
    const int kofs = (lane >> 4) * 8;
    const int KT = NH / 32;

    floatx4 pa[4], pg[4], pu[4];   // prefetch registers
    #pragma unroll
    for (int r = 0; r < 4; ++r) {
        const size_t off = (size_t)(srow + r * 32) * NH + scol;
        pa[r] = *(const floatx4*)(Ab + off);
        pg[r] = *(const floatx4*)(Gb + off);
        pu[r] = *(const floatx4*)(Ub + off);
    }

    for (int kt = 0; kt < KT; ++kt) {
        __builtin_amdgcn_s_barrier();   // A: all waves done reading LDS
        #pragma unroll
        for (int r = 0; r < 4; ++r) {
            const int row = srow + r * 32;
            *(uintx2*)&As [row][scol] = pack4(pa[r]);
            *(uintx2*)&Bgs[row][scol] = pack4(pg[r]);
            *(uintx2*)&Bus[row][scol] = pack4(pu[r]);
        }
        // issue next tile's loads NOW: they fly across barrier+ds_read+MFMA
        if (kt + 1 < KT) {
            const int k0 = (kt + 1) * 32 + scol;
            #pragma unroll
            for (int r = 0; r < 4; ++r) {
                const size_t off = (size_t)(srow + r * 32) * NH + k0;
                pa[r] = *(const floatx4*)(Ab + off);
                pg[r] = *(const floatx4*)(Gb + off);
                pu[r] = *(const floatx4*)(Ub + off);
            }
        }
        asm volatile("s_waitcnt lgkmcnt(0)" ::: "memory");  // ds_writes visible
        __builtin_amdgcn_s_barrier();   // B: tile staged

        short8 af[4], gf[4], uf[4];
        #pragma unroll
        for (int m = 0; m < 4; ++m)
            af[m] = *(const short8*)&As[wr * 64 + m * 16 + frow][kofs];
        #pragma unroll
        for (int n = 0; n < 4; ++n) {
            gf[n] = *(const short8*)&Bgs[wc * 64 + n * 16 + frow][kofs];
            uf[n] = *(const short8*)&Bus[wc * 64 + n * 16 + frow][kofs];
        }
        #pragma unroll
        for (int m = 0; m < 4; ++m)
            #pragma unroll
            for (int n = 0; n < 4; ++n) {
                accg[m][n] = __builtin_amdgcn_mfma_f32_16x16x32_bf16(
                    af[m], gf[n], accg[m][n], 0, 0, 0);
                accu[m][n] = __builtin_amdgcn_mfma_f32_16x16x32_bf16(
                    af[m], uf[n], accu[m][n], 0, 0, 0);
            }
    }

    // Epilogue: silu(gate)*up -> bf16. C/D: col=lane&15, row=(lane>>4)*4+reg.
    const int ccol  = lane & 15;
    const int crow0 = (lane >> 4) * 4;
    const size_t hbase = ((size_t)e * NT + (size_t)tm * 128) * NI + ti * 128;
    #pragma unroll
    for (int m = 0; m < 4; ++m)
        #pragma unroll
        for (int n = 0; n < 4; ++n)
            #pragma unroll
            for (int j = 0; j < 4; ++j) {
                const float g = accg[m][n][j];
                const float u = accu[m][n][j];
                const float h = (g / (1.f + __expf(-g))) * u;
                const int row = wr * 64 + m * 16 + crow0 + j;
                const int col = wc * 64 + n * 16 + ccol;
                hidden[hbase + (size_t)row * NI + col] = f2bf(h);
            }
}

// ---------------------------------------------------------------------------
// Kernel 2: down projection. A = hidden [T,I] bf16, B = down [H,I] f32.
// ---------------------------------------------------------------------------
__global__ __launch_bounds__(256) void moe_down(
    const ushort* __restrict__ hidden, const float* __restrict__ down,
    float* __restrict__ out)
{
    __shared__ ushort As[128][40];
    __shared__ ushort Bs[128][40];

    // 2048 blocks, chunk 256
    const int bid = blockIdx.x;
    const int wg  = (bid & 7) * (2048 / 8) + (bid >> 3);
    const int e   = wg >> 6;
    const int rem = wg & 63;
    const int tn  = rem & 15;   // H tile
    const int tm  = rem >> 4;   // T tile

    const int tid  = threadIdx.x;
    const int lane = tid & 63;
    const int wave = tid >> 6;
    const int wr = wave >> 1, wc = wave & 1;

    const ushort* Ab = hidden + ((size_t)e * NT + (size_t)tm * 128) * NI;
    const float*  Bb = down + (size_t)e * NH * NI + (size_t)(tn * 128) * NI;

    const int a_row = tid >> 2;        // 0..63
    const int a_col = (tid & 3) * 8;   // 0,8,16,24
    const int srow = tid >> 3;
    const int scol = (tid & 7) * 4;

    floatx4 acc[4][4];
    #pragma unroll
    for (int m = 0; m < 4; ++m)
        #pragma unroll
        for (int n = 0; n < 4; ++n) acc[m][n] = (floatx4)0.f;

    const int frow = lane & 15;
    const int kofs = (lane >> 4) * 8;
    const int KT = NI / 32;

    short8 pha0, pha1;
    floatx4 pb[4];
    pha0 = *(const short8*)(Ab + (size_t)a_row * NI + a_col);
    pha1 = *(const short8*)(Ab + (size_t)(a_row + 64) * NI + a_col);
    #pragma unroll
    for (int r = 0; r < 4; ++r)
        pb[r] = *(const floatx4*)(Bb + (size_t)(srow + r * 32) * NI + scol);

    for (int kt = 0; kt < KT; ++kt) {
        __builtin_amdgcn_s_barrier();
        *(short8*)&As[a_row][a_col]      = pha0;
        *(short8*)&As[a_row + 64][a_col] = pha1;
        #pragma unroll
        for (int r = 0; r < 4; ++r)
            *(uintx2*)&Bs[srow + r * 32][scol] = pack4(pb[r]);
        if (kt + 1 < KT) {
            const int k0 = (kt + 1) * 32;
            pha0 = *(const short8*)(Ab + (size_t)a_row * NI + k0 + a_col);
            pha1 = *(const short8*)(Ab + (size_t)(a_row + 64) * NI + k0 + a_col);
            #pragma unroll
            for (int r = 0; r < 4; ++r)
                pb[r] = *(const floatx4*)(Bb + (size_t)(srow + r * 32) * NI + k0 + scol);
        }
        asm volatile("s_waitcnt lgkmcnt(0)" ::: "memory");
        __builtin_amdgcn_s_barrier();

        short8 af[4], bf[4];
        #pragma unroll
        for (int m = 0; m < 4; ++m)
            af[m] = *(const short8*)&As[wr * 64 + m * 16 + frow][kofs];
        #pragma unroll
        for (int n = 0; n < 4; ++n)
            bf[n] = *(const short8*)&Bs[wc * 64 + n * 16 + frow][kofs];
        #pragma unroll
        for (int m = 0; m < 4; ++m)
            #pragma unroll
            for (int n = 0; n < 4; ++n)
                acc[m][n] = __builtin_amdgcn_mfma_f32_16x16x32_bf16(
                    af[m], bf[n], acc[m][n], 0, 0, 0);
    }

    const int ccol  = lane & 15;
    const int crow0 = (lane >> 4) * 4;
    float* Ob = out + ((size_t)e * NT + (size_t)tm * 128) * NH + tn * 128;
    #pragma unroll
    for (int m = 0; m < 4; ++m)
        #pragma unroll
        for (int n = 0; n < 4; ++n)
            #pragma unroll
            for (int j = 0; j < 4; ++j) {
                const int row = wr * 64 + m * 16 + crow0 + j;
                const int col = wc * 64 + n * 16 + ccol;
                Ob[(size_t)row * NH + col] = acc[m][n][j];
            }
}

extern "C" void kernel_launch(void* const* d_in, const int* in_sizes, int n_in,
                              void* d_out, int out_size, void* d_ws, size_t ws_size,
                              hipStream_t stream) {
    const float* rin  = (const float*)d_in[0];   // [E,T,H]
    const float* gate = (const float*)d_in[1];   // [E,I,H]
    const float* up   = (const float*)d_in[2];   // [E,I,H]
    const float* down = (const float*)d_in[3];   // [E,H,I]
    float* out = (float*)d_out;                  // [E*T, H]
    ushort* hidden = (ushort*)d_ws;              // [E,T,I] bf16, 24 MB

    dim3 blk(256);
    moe_gateup<<<dim3(768), blk, 0, stream>>>(rin, gate, up, hidden);
    moe_down<<<dim3(2048), blk, 0, stream>>>(hidden, down, out);
}

// Round 3
// 383.985 us; speedup vs baseline: 1.3984x; 1.0485x over previous
//
#include <hip/hip_runtime.h>

// Qwen3 MoE experts: per-expert SwiGLU MLP.
//   gate = rin @ gate_proj^T ; up = rin @ up_proj^T
//   hidden = silu(gate) * up ; out = hidden @ down_proj^T
// E=32, T=512, H=2048, I=768. f32 inputs; bf16 MFMA, f32 accum.
// ws: hidden [E][T][I] bf16 = 24 MB.
//
// R2: stage f32 tiles straight into LDS with global_load_lds(16B) —
//     zero staging VGPRs/VALU. Convert f32->bf16 at fragment-read time via
//     v_cvt_pk_bf16_f32. Bank conflicts on stride-128B reads fixed by
//     XOR-swizzling the per-lane GLOBAL source (linear LDS dest, rule #21)
//     and reading with the same XOR. Single 48KB buffer, 2-barrier loop.

#define NE 32
#define NT 512
#define NH 2048
#define NI 768

typedef short        short8  __attribute__((ext_vector_type(8)));
typedef float        floatx4 __attribute__((ext_vector_type(4)));
typedef __attribute__((address_space(1))) const unsigned int g_u32;
typedef __attribute__((address_space(3))) unsigned int l_u32;

__device__ __forceinline__ void gl_lds16(const void* g, void* l) {
    __builtin_amdgcn_global_load_lds((g_u32*)g, (l_u32*)l, 16, 0, 0);
}

__device__ __forceinline__ unsigned int cvt_pk_bf16(float lo, float hi) {
    unsigned int r;
    asm("v_cvt_pk_bf16_f32 %0, %1, %2" : "=v"(r) : "v"(lo), "v"(hi));
    return r;
}

// two f32x4 (8 consecutive K values) -> one bf16x8 MFMA fragment
__device__ __forceinline__ short8 frag8(floatx4 x0, floatx4 x1) {
    union { unsigned int u[4]; short8 s; } t;
    t.u[0] = cvt_pk_bf16(x0[0], x0[1]);
    t.u[1] = cvt_pk_bf16(x0[2], x0[3]);
    t.u[2] = cvt_pk_bf16(x1[0], x1[1]);
    t.u[3] = cvt_pk_bf16(x1[2], x1[3]);
    return t.s;
}

__device__ __forceinline__ ushort f2bf(float f) {
    union { float f; unsigned int u; } v; v.f = f;
    unsigned int r = v.u + 0x7fffu + ((v.u >> 16) & 1u);
    return (ushort)(r >> 16);
}

// ---------------------------------------------------------------------------
// Kernel 1: fused gate+up + SwiGLU -> hidden(bf16).
// BM=128(T) x BN=128(I), BK=32 over H; 4 waves (2x2), 64x64/wave, 4x4 frags.
// LDS: three f32 tiles [128][32], linear (global_load_lds), source-swizzled.
// ---------------------------------------------------------------------------
__global__ __launch_bounds__(256, 2) void moe_gateup(
    const float* __restrict__ rin, const float* __restrict__ gate,
    const float* __restrict__ up, ushort* __restrict__ hidden)
{
    __shared__ float As[128][32];
    __shared__ float Gs[128][32];
    __shared__ float Us[128][32];

    // XCD-bijective swizzle (768 % 8 == 0, chunk 96)
    const int bid = blockIdx.x;
    const int wg  = (bid & 7) * (768 / 8) + (bid >> 3);
    const int e   = wg / 24;
    const int rem = wg % 24;
    const int ti  = rem % 6;
    const int tm  = rem / 6;

    const int tid  = threadIdx.x;
    const int lane = tid & 63;
    const int wave = tid >> 6;
    const int wr = wave >> 1, wc = wave & 1;

    const float* Ab = rin  + (size_t)e * NT * NH + (size_t)(tm * 128) * NH;
    const float* Gb = gate + (size_t)e * NI * NH + (size_t)(ti * 128) * NH;
    const float* Ub = up   + (size_t)e * NI * NH + (size_t)(ti * 128) * NH;

    // staging geometry: inst g covers rows [g*8, g*8+8); lane -> row g*8+(l>>3),
    // chunk l&7 (16B chunks, 8 per 128B row). Source chunk = (l&7) ^ (row&7).
    const int lr = lane >> 3;
    const int lc = lane & 7;

    floatx4 accg[4][4], accu[4][4];
    #pragma unroll
    for (int m = 0; m < 4; ++m)
        #pragma unroll
        for (int n = 0; n < 4; ++n) {
            accg[m][n] = (floatx4)0.f;
            accu[m][n] = (floatx4)0.f;
        }

    const int frow = lane & 15;
    const int h    = lane >> 4;
    const int rb   = frow & 7;
    const int c0   = (2 * h) ^ rb;        // swizzled chunk of f32[8h..8h+4)
    const int c1   = (2 * h + 1) ^ rb;    // swizzled chunk of f32[8h+4..8h+8)
    const int KT = NH / 32;

    for (int kt = 0; kt < KT; ++kt) {
        const int k0 = kt * 32;
        __builtin_amdgcn_s_barrier();   // all waves done reading prev tile
        #pragma unroll
        for (int i = 0; i < 4; ++i) {
            const int g = wave * 4 + i;
            const int r = g * 8 + lr;
            const int cs = lc ^ (r & 7);
            const size_t so = (size_t)r * NH + k0 + cs * 4;
            gl_lds16(Ab + so, &As[g * 8][0]);
            gl_lds16(Gb + so, &Gs[g * 8][0]);
            gl_lds16(Ub + so, &Us[g * 8][0]);
        }
        asm volatile("s_waitcnt vmcnt(0)" ::: "memory");
        __builtin_amdgcn_s_barrier();   // tile staged

        short8 af[4], gf[4], uf[4];
        #pragma unroll
        for (int m = 0; m < 4; ++m) {
            const int R = wr * 64 + m * 16 + frow;
            af[m] = frag8(*(const floatx4*)&As[R][c0 * 4],
                          *(const floatx4*)&As[R][c1 * 4]);
        }
        #pragma unroll
        for (int n = 0; n < 4; ++n) {
            const int R = wc * 64 + n * 16 + frow;
            gf[n] = frag8(*(const floatx4*)&Gs[R][c0 * 4],
                          *(const floatx4*)&Gs[R][c1 * 4]);
            uf[n] = frag8(*(const floatx4*)&Us[R][c0 * 4],
                          *(const floatx4*)&Us[R][c1 * 4]);
        }
        #pragma unroll
        for (int m = 0; m < 4; ++m)
            #pragma unroll
            for (int n = 0; n < 4; ++n) {
                accg[m][n] = __builtin_amdgcn_mfma_f32_16x16x32_bf16(
                    af[m], gf[n], accg[m][n], 0, 0, 0);
                accu[m][n] = __builtin_amdgcn_mfma_f32_16x16x32_bf16(
                    af[m], uf[n], accu[m][n], 0, 0, 0);
            }
    }

    // Epilogue: silu(g)*u -> bf16. C/D: col=lane&15, row=(lane>>4)*4+reg.
    const int ccol  = lane & 15;
    const int crow0 = (lane >> 4) * 4;
    const size_t hbase = ((size_t)e * NT + (size_t)tm * 128) * NI + ti * 128;
    #pragma unroll
    for (int m = 0; m < 4; ++m)
        #pragma unroll
        for (int n = 0; n < 4; ++n)
            #pragma unroll
            for (int j = 0; j < 4; ++j) {
                const float g = accg[m][n][j];
                const float u = accu[m][n][j];
                const float hh = (g / (1.f + __expf(-g))) * u;
                const int row = wr * 64 + m * 16 + crow0 + j;
                const int col = wc * 64 + n * 16 + ccol;
                hidden[hbase + (size_t)row * NI + col] = f2bf(hh);
            }
}

// ---------------------------------------------------------------------------
// Kernel 2: down projection. A = hidden [T,I] bf16 (gload_lds direct),
// B = down [H,I] f32 (f32-in-LDS + cvt at frag read). BK=32 over I.
// ---------------------------------------------------------------------------
__global__ __launch_bounds__(256, 2) void moe_down(
    const ushort* __restrict__ hidden, const float* __restrict__ down,
    float* __restrict__ out)
{
    __shared__ ushort As[128][32];   // bf16, rows 64B = 4 chunks of 16B
    __shared__ float  Bs[128][32];   // f32, rows 128B = 8 chunks

    const int bid = blockIdx.x;
    const int wg  = (bid & 7) * (2048 / 8) + (bid >> 3);
    const int e   = wg >> 6;
    const int rem = wg & 63;
    const int tn  = rem & 15;
    const int tm  = rem >> 4;

    const int tid  = threadIdx.x;
    const int lane = tid & 63;
    const int wave = tid >> 6;
    const int wr = wave >> 1, wc = wave & 1;

    const ushort* Ab = hidden + ((size_t)e * NT + (size_t)tm * 128) * NI;
    const float*  Bb = down + (size_t)e * NH * NI + (size_t)(tn * 128) * NI;

    floatx4 acc[4][4];
    #pragma unroll
    for (int m = 0; m < 4; ++m)
        #pragma unroll
        for (int n = 0; n < 4; ++n) acc[m][n] = (floatx4)0.f;

    const int frow = lane & 15;
    const int h    = lane >> 4;
    // A (bf16): one 16B chunk per frag; 4 chunks/row, swizzle ^(row&3)
    const int ca   = h ^ (frow & 3);
    // B (f32): two 16B chunks per frag; 8 chunks/row, swizzle ^(row&7)
    const int rb   = frow & 7;
    const int c0   = (2 * h) ^ rb;
    const int c1   = (2 * h + 1) ^ rb;
    const int KT = NI / 32;

    for (int kt = 0; kt < KT; ++kt) {
        const int k0 = kt * 32;
        __builtin_amdgcn_s_barrier();
        // A: 8KB = 8 insts; inst g covers rows [g*16, g*16+16)
        #pragma unroll
        for (int i = 0; i < 2; ++i) {
            const int g = wave * 2 + i;
            const int r = g * 16 + (lane >> 2);
            const int cs = (lane & 3) ^ (r & 3);
            gl_lds16(Ab + (size_t)r * NI + k0 + cs * 8, &As[g * 16][0]);
        }
        // B: 16KB = 16 insts; inst g covers rows [g*8, g*8+8)
        #pragma unroll
        for (int i = 0; i < 4; ++i) {
            const int g = wave * 4 + i;
            const int r = g * 8 + (lane >> 3);
            const int cs = (lane & 7) ^ (r & 7);
            gl_lds16(Bb + (size_t)r * NI + k0 + cs * 4, &Bs[g * 8][0]);
        }
        asm volatile("s_waitcnt vmcnt(0)" ::: "memory");
        __builtin_amdgcn_s_barrier();

        short8 af[4], bf[4];
        #pragma unroll
        for (int m = 0; m < 4; ++m) {
            const int R = wr * 64 + m * 16 + frow;
            af[m] = *(const short8*)&As[R][ca * 8];
        }
        #pragma unroll
        for (int n = 0; n < 4; ++n) {
            const int R = wc * 64 + n * 16 + frow;
            bf[n] = frag8(*(const floatx4*)&Bs[R][c0 * 4],
                          *(const floatx4*)&Bs[R][c1 * 4]);
        }
        #pragma unroll
        for (int m = 0; m < 4; ++m)
            #pragma unroll
            for (int n = 0; n < 4; ++n)
                acc[m][n] = __builtin_amdgcn_mfma_f32_16x16x32_bf16(
                    af[m], bf[n], acc[m][n], 0, 0, 0);
    }

    const int ccol  = lane & 15;
    const int crow0 = (lane >> 4) * 4;
    float* Ob = out + ((size_t)e * NT + (size_t)tm * 128) * NH + tn * 128;
    #pragma unroll
    for (int m = 0; m < 4; ++m)
        #pragma unroll
        for (int n = 0; n < 4; ++n)
            #pragma unroll
            for (int j = 0; j < 4; ++j) {
                const int row = wr * 64 + m * 16 + crow0 + j;
                const int col = wc * 64 + n * 16 + ccol;
                Ob[(size_t)row * NH + col] = acc[m][n][j];
            }
}

extern "C" void kernel_launch(void* const* d_in, const int* in_sizes, int n_in,
                              void* d_out, int out_size, void* d_ws, size_t ws_size,
                              hipStream_t stream) {
    const float* rin  = (const float*)d_in[0];
    const float* gate = (const float*)d_in[1];
    const float* up   = (const float*)d_in[2];
    const float* down = (const float*)d_in[3];
    float* out = (float*)d_out;
    ushort* hidden = (ushort*)d_ws;

    dim3 blk(256);
    moe_gateup<<<dim3(768), blk, 0, stream>>>(rin, gate, up, hidden);
    moe_down<<<dim3(2048), blk, 0, stream>>>(hidden, down, out);
}